// Round 10
// baseline (193.681 us; speedup 1.0000x reference)
//
#include <hip/hip_runtime.h>
#include <hip/hip_cooperative_groups.h>

namespace cg = cooperative_groups;

#define K_PRE 6   // device-gated pre-launched steps (bench data halts at T~3)

// ---- ws float offsets (all float4-aligned) ----
#define O_CUM    0      // cum after step j, 128 slots
#define O_DONE   128    // done after step j, 128 slots
#define O_WSUM   256
#define O_PONDER 257
#define O_AXB    512    // x-half dot + bh cache, 4096
#define O_P0     4608   // parity-0 A-partials (2 x 4096)
#define O_Q0     12800  // parity-1 A-partials (2 x 4096)
#define O_ACCH   20992  // hid accumulator, 4096
#define O_NS0    25088  // tail handoff state
#define O_NS1    29184

// Swizzled LDS index: +1 dword pad every 32 -> 2-way bank alias only (free).
__device__ __forceinline__ int zi(int c) { return c + (c >> 5); }

// Stage up to 512 float4 (8 KB) into this wave's LDS buffer via
// global_load_lds dwordx4: zero VGPR cost -> in-flight bytes limited by LDS,
// not the VGPR file (the ~2.4 TB/s wall of rounds 2-9).
// Per-lane global src (16B-aligned, clamped to nf4-1); wave-uniform LDS dest.
__device__ __forceinline__ void stage512(const float4* __restrict__ g, int nf4,
                                         float4* wb, int lane) {
    #pragma unroll
    for (int k = 0; k < 8; ++k) {
        int jj = (k << 6) + lane;
        if (jj >= nf4) jj = nf4 - 1;           // clamped duplicate read, data unused
        __builtin_amdgcn_global_load_lds(
            (const __attribute__((address_space(1))) void*)(g + jj),
            (__attribute__((address_space(3))) void*)(wb + (k << 6)), 16, 0, 0);
    }
}

#define WAIT_VM0   asm volatile("s_waitcnt vmcnt(0)" ::: "memory")
#define WAIT_LGKM0 asm volatile("s_waitcnt lgkmcnt(0)" ::: "memory")

// ---------- k_step(i): [ns(i-1)+halt(i-1), redundant per block] + [A(i)] ----------
// 256 blocks x 1024 thr = 1 block/CU (148 KB LDS), wave = one row; each wave
// computes both column-quarter partials (order identical to r9's two waves).
__global__ __launch_bounds__(1024) void k_step(
    int i,
    const float* __restrict__ x, const float* __restrict__ s,
    const float* __restrict__ Wh, const float* __restrict__ bh,
    const float* __restrict__ Whalt, const float* __restrict__ bhalt,
    float* __restrict__ wsb)
{
    const int tid  = threadIdx.x;
    const int lane = tid & 63;
    const int wid  = tid >> 6;
    const int row  = blockIdx.x * 16 + wid;    // 0..4095

    __shared__ float  zb[4225];
    __shared__ float  red[16];
    __shared__ float4 wbuf[16][512];           // 8 KB per wave
    float4* wb = wbuf[wid];

    const int pre = (4 - ((row + 1) & 3)) & 3; // (row*8193+start)%4 peel, start%4==1
    float* pbW = wsb + ((i & 1) ? O_Q0 : O_P0);
    const float* WhR = Wh + (size_t)row * 8193;

    if (i == 0) {
        // ---- x-half (cols 1..4096): dot + AXB/pb cache ----
        for (int k = tid; k < 4096; k += 1024) zb[zi(k)] = x[k];
        __syncthreads();
        {
            const int start = 1, cs = start + pre, n4h = (4096 - pre) >> 2;
            const float4* g = reinterpret_cast<const float4*>(WhR + cs);
            stage512(g, 512, wb, lane);
            float a0=0.f, a1=0.f, a2=0.f, a3=0.f;
            if (lane < pre) a0 = WhR[start + lane] * zb[zi(lane)];
            WAIT_VM0;
            #pragma unroll 8
            for (int j = lane; j < 512; j += 64) {
                float4 wv = wb[j]; int c = pre + 4 * j;
                a0 += wv.x * zb[zi(c)];   a1 += wv.y * zb[zi(c + 1)];
                a2 += wv.z * zb[zi(c + 2)]; a3 += wv.w * zb[zi(c + 3)];
            }
            WAIT_LGKM0;
            stage512(g + 512, n4h - 512, wb, lane);
            WAIT_VM0;
            #pragma unroll 8
            for (int j = 512 + lane; j < n4h; j += 64) {
                float4 wv = wb[j - 512]; int c = pre + 4 * j;
                a0 += wv.x * zb[zi(c)];   a1 += wv.y * zb[zi(c + 1)];
                a2 += wv.z * zb[zi(c + 2)]; a3 += wv.w * zb[zi(c + 3)];
            }
            for (int c = pre + 4 * n4h + lane; c < 4096; c += 64)
                a0 += WhR[start + c] * zb[zi(c)];
            float acc = (a0 + a1) + (a2 + a3);
            #pragma unroll
            for (int off = 32; off; off >>= 1) acc += __shfl_xor(acc, off, 64);
            if (lane == 0) {
                wsb[O_AXB + row] = acc + bh[row];   // cached x-half (+bias)
                pbW[row]         = acc + WhR[0];    // step-0 partial incl. flag col
            }
        }
        __syncthreads();                            // all zb(x) reads done
        // ---- s-half (cols 4097..8192) ----
        for (int k = tid; k < 4096; k += 1024) zb[zi(k)] = s[k];
        __syncthreads();
        {
            const int start = 4097, cs = start + pre, n4h = (4096 - pre) >> 2;
            const float4* g = reinterpret_cast<const float4*>(WhR + cs);
            WAIT_LGKM0;
            stage512(g, 512, wb, lane);
            float a0=0.f, a1=0.f, a2=0.f, a3=0.f;
            if (lane < pre) a0 = WhR[start + lane] * zb[zi(lane)];
            WAIT_VM0;
            #pragma unroll 8
            for (int j = lane; j < 512; j += 64) {
                float4 wv = wb[j]; int c = pre + 4 * j;
                a0 += wv.x * zb[zi(c)];   a1 += wv.y * zb[zi(c + 1)];
                a2 += wv.z * zb[zi(c + 2)]; a3 += wv.w * zb[zi(c + 3)];
            }
            WAIT_LGKM0;
            stage512(g + 512, n4h - 512, wb, lane);
            WAIT_VM0;
            #pragma unroll 8
            for (int j = 512 + lane; j < n4h; j += 64) {
                float4 wv = wb[j - 512]; int c = pre + 4 * j;
                a0 += wv.x * zb[zi(c)];   a1 += wv.y * zb[zi(c + 1)];
                a2 += wv.z * zb[zi(c + 2)]; a3 += wv.w * zb[zi(c + 3)];
            }
            for (int c = pre + 4 * n4h + lane; c < 4096; c += 64)
                a0 += WhR[start + c] * zb[zi(c)];
            float acc = (a0 + a1) + (a2 + a3);
            #pragma unroll
            for (int off = 32; off; off >>= 1) acc += __shfl_xor(acc, off, 64);
            if (lane == 0) pbW[4096 + row] = acc;
        }
        return;
    }

    // ---- idle fast path keeps the scalar chain alive ----
    const float doneB = (i >= 2) ? wsb[O_DONE + i - 2] : 0.0f;
    if (doneB != 0.0f) {
        if (blockIdx.x == 0 && tid == 0) {
            wsb[O_CUM + i - 1]  = wsb[O_CUM + i - 2];
            wsb[O_DONE + i - 1] = 1.0f;
        }
        return;
    }
    const float cumB = (i >= 2) ? wsb[O_CUM + i - 2] : 0.0f;

    // ---- ns(i-1) = pb0 + pb1 + bias; halt logit (redundant, order == r9) ----
    const float* pbR  = wsb + (((i - 1) & 1) ? O_Q0 : O_P0);
    const float* bias = (i == 1) ? bh : (wsb + O_AXB);
    float4 u0 = reinterpret_cast<const float4*>(pbR)[tid];
    float4 u1 = reinterpret_cast<const float4*>(pbR + 4096)[tid];
    float4 bb = reinterpret_cast<const float4*>(bias)[tid];
    float4 hw = reinterpret_cast<const float4*>(Whalt)[tid];
    float4 nsv;
    nsv.x = u0.x + u1.x + bb.x;  nsv.y = u0.y + u1.y + bb.y;
    nsv.z = u0.z + u1.z + bb.z;  nsv.w = u0.w + u1.w + bb.w;
    { int c = 4 * tid;                              // stage FULL state half
      zb[zi(c)]   = nsv.x; zb[zi(c+1)] = nsv.y;
      zb[zi(c+2)] = nsv.z; zb[zi(c+3)] = nsv.w; }
    float part = hw.x*nsv.x + hw.y*nsv.y + hw.z*nsv.z + hw.w*nsv.w;
    #pragma unroll
    for (int off = 32; off; off >>= 1) part += __shfl_xor(part, off, 64);
    if (lane == 0) red[wid] = part;
    __syncthreads();                                // zb(ns) + red ready
    float logit = bhalt[0];
    #pragma unroll
    for (int j = 0; j < 16; ++j) logit += red[j];   // identical everywhere
    const float p         = 1.0f / (1.0f + expf(-logit));
    const bool  will_halt = (cumB + p >= 0.99f) || ((i - 1) == 127);
    const float w         = will_halt ? (1.0f - cumB) : p;

    if (blockIdx.x == 0 && tid == 0) {
        wsb[O_CUM + i - 1]  = cumB + p;
        wsb[O_DONE + i - 1] = will_halt ? 1.0f : 0.0f;
        if (i == 1) wsb[O_WSUM] = w; else wsb[O_WSUM] += w;
        if (will_halt) wsb[O_PONDER] = (float)(i - 1) + 1.0f + (1.0f - cumB);
    }
    if (blockIdx.x == 0) {                          // hid accumulator, block 0
        float4* aH = reinterpret_cast<float4*>(wsb + O_ACCH);
        if (i == 1) {
            float4 t; t.x = w*nsv.x; t.y = w*nsv.y; t.z = w*nsv.z; t.w = w*nsv.w;
            aH[tid] = t;
        } else {
            float4 t = aH[tid];
            t.x += w*nsv.x; t.y += w*nsv.y; t.z += w*nsv.z; t.w += w*nsv.w;
            aH[tid] = t;
        }
    }
    if (i == K_PRE && blockIdx.x == 1)              // handoff for coop tail
        reinterpret_cast<float4*>(wsb + (((i - 1) & 1) ? O_NS1 : O_NS0))[tid] = nsv;

    // ---- A(i): both state-quarter dots per wave (LDS-staged W) ----
    if (i < K_PRE && !will_halt) {
        #pragma unroll
        for (int q = 0; q < 2; ++q) {
            const int startq = 4097 + 2048 * q;
            const int csq    = startq + pre;
            const int n4q    = (2048 - pre) >> 2;
            const int zo     = 2048 * q;
            const float4* gq = reinterpret_cast<const float4*>(WhR + csq);
            WAIT_LGKM0;                              // own ds_reads retired
            stage512(gq, n4q, wb, lane);
            float a0=0.f, a1=0.f, a2=0.f, a3=0.f;
            if (lane < pre) a0 = WhR[startq + lane] * zb[zi(zo + lane)];
            WAIT_VM0;
            #pragma unroll 8
            for (int j = lane; j < n4q; j += 64) {
                float4 wv = wb[j]; int c = zo + pre + 4 * j;
                a0 += wv.x * zb[zi(c)];   a1 += wv.y * zb[zi(c + 1)];
                a2 += wv.z * zb[zi(c + 2)]; a3 += wv.w * zb[zi(c + 3)];
            }
            for (int c2 = pre + 4 * n4q + lane; c2 < 2048; c2 += 64)
                a0 += WhR[startq + c2] * zb[zi(zo + c2)];
            float acc = (a0 + a1) + (a2 + a3);
            #pragma unroll
            for (int off = 32; off; off >>= 1) acc += __shfl_xor(acc, off, 64);
            if (lane == 0) pbW[(q << 12) + row] = acc;
        }
    }
}

// ---------- cooperative tail for T > K_PRE (instant uniform exit on bench data) ----------
__global__ __launch_bounds__(1024, 4) void k_tail(
    const float* __restrict__ x, const float* __restrict__ Wh,
    const float* __restrict__ bh, const float* __restrict__ Whalt,
    const float* __restrict__ bhalt, float* __restrict__ wsb)
{
    cg::grid_group grid = cg::this_grid();
    if (wsb[O_DONE + K_PRE - 1] != 0.0f) return;

    const int tid  = threadIdx.x;
    const int lane = tid & 63;
    const int wid  = tid >> 6;
    const int gw   = blockIdx.x * 16 + wid;

    float* ns0 = wsb + O_NS0;
    float* ns1 = wsb + O_NS1;

    __shared__ float xl[4096];
    __shared__ float red[16];
    for (int k = tid; k < 4096; k += 1024) xl[k] = x[k];
    __syncthreads();

    const float* WhR   = Wh + (size_t)gw * 8193;
    const float4* wh4  = reinterpret_cast<const float4*>(Whalt);
    const float bh_r   = bh[gw];
    const float bhalt0 = bhalt[0];

    float cum = wsb[O_CUM + K_PRE - 1];
    float wsuml = 0.f, ponder = 0.f;

    for (int i = K_PRE; i < 128; ++i) {
        const float* st = (i & 1) ? ns0 : ns1;
        float*      nsc = (i & 1) ? ns1 : ns0;

        float acc = 0.0f;
        #pragma unroll 8
        for (int k = lane; k < 4096; k += 64) acc += WhR[1 + k] * xl[k];
        #pragma unroll 8
        for (int k = lane; k < 4096; k += 64) acc += WhR[4097 + k] * st[k];
        #pragma unroll
        for (int off = 32; off; off >>= 1) acc += __shfl_xor(acc, off, 64);
        if (lane == 0) nsc[gw] = acc + bh_r;
        grid.sync();

        const float4* ns4 = reinterpret_cast<const float4*>(nsc);
        float4 nv = ns4[tid], hw = wh4[tid];
        float part = hw.x*nv.x + hw.y*nv.y + hw.z*nv.z + hw.w*nv.w;
        #pragma unroll
        for (int off = 32; off; off >>= 1) part += __shfl_xor(part, off, 64);
        if (lane == 0) red[wid] = part;
        __syncthreads();
        float logit = bhalt0;
        #pragma unroll
        for (int j = 0; j < 16; ++j) logit += red[j];
        const float p         = 1.0f / (1.0f + expf(-logit));
        const bool  will_halt = (cum + p >= 0.99f) || (i == 127);
        const float w         = will_halt ? (1.0f - cum) : p;

        if (blockIdx.x == 0) {
            float4* aH = reinterpret_cast<float4*>(wsb + O_ACCH);
            float4 t = aH[tid];
            t.x += w*nv.x; t.y += w*nv.y; t.z += w*nv.z; t.w += w*nv.w;
            aH[tid] = t;
        }
        wsuml += w;

        if (will_halt) { ponder = (float)i + 1.0f + (1.0f - cum); break; }
        cum += p;
        grid.sync();
    }

    if (blockIdx.x == 0 && tid == 0) {
        wsb[O_WSUM]  += wsuml;
        wsb[O_PONDER] = ponder;
    }
}

// ---------- k_out: out = Wo @ hid + wsum*bo (Wo read once, LDS-staged) ----------
__global__ __launch_bounds__(1024) void k_out(
    const float* __restrict__ Wo, const float* __restrict__ bo,
    const float* __restrict__ wsb, float* __restrict__ out)
{
    const int tid  = threadIdx.x;
    const int lane = tid & 63;
    const int wid  = tid >> 6;
    const int row  = blockIdx.x * 16 + wid;

    __shared__ float  zb[4225];
    __shared__ float4 wbuf[16][512];
    float4* wb = wbuf[wid];

    for (int k = tid; k < 4096; k += 1024) zb[zi(k)] = wsb[O_ACCH + k];
    __syncthreads();

    const float4* WoR4 = reinterpret_cast<const float4*>(Wo + (size_t)row * 4096);
    stage512(WoR4, 512, wb, lane);
    float b0=0.f, b1=0.f, b2=0.f, b3=0.f;
    WAIT_VM0;
    #pragma unroll 8
    for (int j = lane; j < 512; j += 64) {
        float4 wv = wb[j]; int c = 4 * j;
        b0 += wv.x * zb[zi(c)];   b1 += wv.y * zb[zi(c + 1)];
        b2 += wv.z * zb[zi(c + 2)]; b3 += wv.w * zb[zi(c + 3)];
    }
    WAIT_LGKM0;
    stage512(WoR4 + 512, 512, wb, lane);
    WAIT_VM0;
    #pragma unroll 8
    for (int j = 512 + lane; j < 1024; j += 64) {
        float4 wv = wb[j - 512]; int c = 4 * j;
        b0 += wv.x * zb[zi(c)];   b1 += wv.y * zb[zi(c + 1)];
        b2 += wv.z * zb[zi(c + 2)]; b3 += wv.w * zb[zi(c + 3)];
    }
    float acc = (b0 + b1) + (b2 + b3);
    #pragma unroll
    for (int off = 32; off; off >>= 1) acc += __shfl_xor(acc, off, 64);
    if (lane == 0) out[row] = acc + wsb[O_WSUM] * bo[row];

    const int gtid = blockIdx.x * 1024 + tid;
    if (gtid < 4096) out[4096 + gtid] = wsb[O_ACCH + gtid];
    if (gtid == 0)   out[8192] = wsb[O_PONDER];
}

extern "C" void kernel_launch(void* const* d_in, const int* in_sizes, int n_in,
                              void* d_out, int out_size, void* d_ws, size_t ws_size,
                              hipStream_t stream) {
    const float* x     = (const float*)d_in[0];
    const float* s     = (const float*)d_in[1];
    const float* Wh    = (const float*)d_in[2];
    const float* bh    = (const float*)d_in[3];
    const float* Whalt = (const float*)d_in[4];
    const float* bhalt = (const float*)d_in[5];
    const float* Wo    = (const float*)d_in[6];
    const float* bo    = (const float*)d_in[7];
    float* out = (float*)d_out;
    float* wsb = (float*)d_ws;

    for (int i = 0; i <= K_PRE; ++i)
        k_step<<<256, 1024, 0, stream>>>(i, x, s, Wh, bh, Whalt, bhalt, wsb);

    {   // cooperative tail for T > K_PRE
        void* args[] = { (void*)&x, (void*)&Wh, (void*)&bh, (void*)&Whalt,
                         (void*)&bhalt, (void*)&wsb };
        hipLaunchCooperativeKernel((void*)k_tail, dim3(256), dim3(1024),
                                   args, 0, stream);
    }
    k_out<<<256, 1024, 0, stream>>>(Wo, bo, wsb, out);
}